// Round 1
// baseline (129.195 us; speedup 1.0000x reference)
//
#include <hip/hip_runtime.h>

#define T0 4096
#define NLEV 5
#define BLOCK 256

__constant__ float c_LO[8] = {
    -0.010597401784997278f, 0.032883011666982945f, 0.030841381835986965f,
    -0.18703481171888114f, -0.02798376941698385f, 0.6308807679295904f,
    0.7148465705525415f, 0.23037781330885523f};
__constant__ float c_HI[8] = {
    -0.23037781330885523f, 0.7148465705525415f, -0.6308807679295904f,
    -0.02798376941698385f, 0.18703481171888114f, 0.030841381835986965f,
    -0.032883011666982945f, -0.010597401784997278f};

// half-sample symmetric reflection: t<0 -> -1-t ; t>=L -> 2L-1-t
// (single reflection suffices: |t| offsets are < 8 <= min L = 134)
__device__ __forceinline__ int symidx(int t, int L) {
    t = (t < 0) ? (-1 - t) : t;
    t = (t >= L) ? (2 * L - 1 - t) : t;
    return t;
}

__global__ __launch_bounds__(BLOCK) void dwt5_kernel(
    const float* __restrict__ x, float* __restrict__ out,
    long long offA, long long offD1, long long offD2, long long offD3,
    long long offD4, long long offD5)
{
    __shared__ float bufA[T0];
    __shared__ float bufB[2051 + 1];

    const int row = blockIdx.x;
    const int tid = threadIdx.x;
    const float* __restrict__ xrow = x + (size_t)row * T0;

    // coalesced float4 load of the whole row into LDS
    for (int j = tid; j < T0 / 4; j += BLOCK) {
        float4 v = reinterpret_cast<const float4*>(xrow)[j];
        bufA[4 * j + 0] = v.x;
        bufA[4 * j + 1] = v.y;
        bufA[4 * j + 2] = v.z;
        bufA[4 * j + 3] = v.w;
    }
    __syncthreads();

    long long dOff[NLEV] = {offD1, offD2, offD3, offD4, offD5};

    float* src = bufA;
    float* dst = bufB;
    int L = T0;
    for (int lev = 0; lev < NLEV; ++lev) {
        const int nOut = (L + 7) >> 1;
        float* __restrict__ dSeg = out + dOff[lev] + (long long)row * nOut;
        float* __restrict__ aSeg = out + offA + (long long)row * nOut;
        for (int i = tid; i < nOut; i += BLOCK) {
            const int base = 2 * i + 1;
            float lo = 0.f, hi = 0.f;
#pragma unroll
            for (int m = 0; m < 8; ++m) {
                const float v = src[symidx(base - m, L)];
                lo = fmaf(c_LO[m], v, lo);
                hi = fmaf(c_HI[m], v, hi);
            }
            dSeg[i] = hi;              // detail straight to global (coalesced)
            if (lev == NLEV - 1) {
                aSeg[i] = lo;          // final approx to global
            } else {
                dst[i] = lo;           // approx feeds next level
            }
        }
        __syncthreads();
        float* tmp = src; src = dst; dst = tmp;
        L = nOut;
    }
}

extern "C" void kernel_launch(void* const* d_in, const int* in_sizes, int n_in,
                              void* d_out, int out_size, void* d_ws, size_t ws_size,
                              hipStream_t stream) {
    const float* x = (const float*)d_in[0];
    float* out = (float*)d_out;

    const int rows = in_sizes[0] / T0;   // 64*64 = 4096
    const int n1 = (T0 + 7) / 2;         // 2051
    const int n2 = (n1 + 7) / 2;         // 1029
    const int n3 = (n2 + 7) / 2;         // 518
    const int n4 = (n3 + 7) / 2;         // 262
    const int n5 = (n4 + 7) / 2;         // 134

    const long long offA  = 0;
    const long long offD5 = offA  + (long long)rows * n5;
    const long long offD4 = offD5 + (long long)rows * n5;
    const long long offD3 = offD4 + (long long)rows * n4;
    const long long offD2 = offD3 + (long long)rows * n3;
    const long long offD1 = offD2 + (long long)rows * n2;

    dwt5_kernel<<<rows, BLOCK, 0, stream>>>(x, out, offA, offD1, offD2, offD3,
                                            offD4, offD5);
}

// Round 2
// 113.806 us; speedup vs baseline: 1.1352x; 1.1352x over previous
//
#include <hip/hip_runtime.h>

#define T0 4096
#define NLEV 5
#define BLOCK 256
#define PAD 6            // left pad; right pad is 7; total 13

// filters reversed so tap k multiplies ext[2i+k]:
// rLO[k] = DEC_LO[7-k], rHI[k] = DEC_HI[7-k]
#define RLO0  0.23037781330885523f
#define RLO1  0.7148465705525415f
#define RLO2  0.6308807679295904f
#define RLO3 -0.02798376941698385f
#define RLO4 -0.18703481171888114f
#define RLO5  0.030841381835986965f
#define RLO6  0.032883011666982945f
#define RLO7 -0.010597401784997278f

#define RHI0 -0.010597401784997278f
#define RHI1 -0.032883011666982945f
#define RHI2  0.030841381835986965f
#define RHI3  0.18703481171888114f
#define RHI4 -0.02798376941698385f
#define RHI5 -0.6308807679295904f
#define RHI6  0.7148465705525415f
#define RHI7 -0.23037781330885523f

__global__ __launch_bounds__(BLOCK) void dwt5_kernel(
    const float* __restrict__ x, float* __restrict__ out,
    long long offA, long long offD1, long long offD2, long long offD3,
    long long offD4, long long offD5)
{
    // extended (padded) buffers: ext[PAD + s] = level sample s
    __shared__ float extA[T0 + 16];
    __shared__ float extB[2051 + 16];

    const int row = blockIdx.x;
    const int tid = threadIdx.x;
    const float* __restrict__ xrow = x + (size_t)row * T0;

    // coalesced float4 load of the row into extA[PAD..], with inline mirrors
    for (int j = tid; j < T0 / 4; j += BLOCK) {
        float4 v = reinterpret_cast<const float4*>(xrow)[j];
        const int b = 4 * j;
        float w[4] = {v.x, v.y, v.z, v.w};
        extA[PAD + b + 0] = w[0];
        extA[PAD + b + 1] = w[1];
        extA[PAD + b + 2] = w[2];
        extA[PAD + b + 3] = w[3];
        if (b < 8) {             // left mirror: ext[5-s] = x[s], s<6
#pragma unroll
            for (int k = 0; k < 4; ++k) {
                const int s = b + k;
                if (s < 6) extA[5 - s] = w[k];
            }
        }
        if (b >= T0 - 8) {       // right mirror: ext[PAD+T0+(T0-1-s)] = x[s], s>=T0-7
#pragma unroll
            for (int k = 0; k < 4; ++k) {
                const int s = b + k;
                if (s >= T0 - 7) extA[PAD + T0 + (T0 - 1 - s)] = w[k];
            }
        }
    }
    __syncthreads();

    const long long dOff[NLEV] = {offD1, offD2, offD3, offD4, offD5};

    float* src = extA;
    float* dst = extB;
    int L = T0;
#pragma unroll
    for (int lev = 0; lev < NLEV; ++lev) {
        const int nOut = (L + 7) >> 1;
        float* __restrict__ dSeg = out + dOff[lev] + (long long)row * nOut;
        float* __restrict__ aSeg = out + offA + (long long)row * nOut;
        const float2* __restrict__ e2 = reinterpret_cast<const float2*>(src);
        for (int i = tid; i < nOut; i += BLOCK) {
            // taps are ext[2i .. 2i+7] -> 4 aligned float2 reads
            const float2 w0 = e2[i + 0];
            const float2 w1 = e2[i + 1];
            const float2 w2 = e2[i + 2];
            const float2 w3 = e2[i + 3];

            float lo, hi;
            lo = RLO0 * w0.x;            hi = RHI0 * w0.x;
            lo = fmaf(RLO1, w0.y, lo);   hi = fmaf(RHI1, w0.y, hi);
            lo = fmaf(RLO2, w1.x, lo);   hi = fmaf(RHI2, w1.x, hi);
            lo = fmaf(RLO3, w1.y, lo);   hi = fmaf(RHI3, w1.y, hi);
            lo = fmaf(RLO4, w2.x, lo);   hi = fmaf(RHI4, w2.x, hi);
            lo = fmaf(RLO5, w2.y, lo);   hi = fmaf(RHI5, w2.y, hi);
            lo = fmaf(RLO6, w3.x, lo);   hi = fmaf(RHI6, w3.x, hi);
            lo = fmaf(RLO7, w3.y, lo);   hi = fmaf(RHI7, w3.y, hi);

            __builtin_nontemporal_store(hi, &dSeg[i]);   // detail out
            if (lev == NLEV - 1) {
                __builtin_nontemporal_store(lo, &aSeg[i]);  // final approx out
            } else {
                dst[PAD + i] = lo;                          // feeds next level
                if (i < 6)          dst[5 - i] = lo;        // left mirror
                if (i >= nOut - 7)  dst[PAD + nOut + (nOut - 1 - i)] = lo; // right mirror
            }
        }
        __syncthreads();
        float* tmp = src; src = dst; dst = tmp;
        L = nOut;
    }
}

extern "C" void kernel_launch(void* const* d_in, const int* in_sizes, int n_in,
                              void* d_out, int out_size, void* d_ws, size_t ws_size,
                              hipStream_t stream) {
    const float* x = (const float*)d_in[0];
    float* out = (float*)d_out;

    const int rows = in_sizes[0] / T0;   // 64*64 = 4096
    const int n1 = (T0 + 7) / 2;         // 2051
    const int n2 = (n1 + 7) / 2;         // 1029
    const int n3 = (n2 + 7) / 2;         // 518
    const int n4 = (n3 + 7) / 2;         // 262
    const int n5 = (n4 + 7) / 2;         // 134

    const long long offA  = 0;
    const long long offD5 = offA  + (long long)rows * n5;
    const long long offD4 = offD5 + (long long)rows * n5;
    const long long offD3 = offD4 + (long long)rows * n4;
    const long long offD2 = offD3 + (long long)rows * n3;
    const long long offD1 = offD2 + (long long)rows * n2;

    dwt5_kernel<<<rows, BLOCK, 0, stream>>>(x, out, offA, offD1, offD2, offD3,
                                            offD4, offD5);
}